// Round 14
// baseline (177.705 us; speedup 1.0000x reference)
//
#include <hip/hip_runtime.h>
#include <hip/hip_fp16.h>

// PolyConv via CSR-gather. Build = block-local LDS counting sort with slim
// 5B edge records:
//   p3: block stages {src|q15(mask)<<17} (u32) + dst (LDS), histograms buckets
//       (g=dst>>8), LDS-scans, scatters ep32(u32)+epd(u8, bucket-local node)
//       grouped-by-bucket WITHIN its contiguous slice; emits lofsT[g][b].
//   scanR: R[g] = sum_b lofsT[g][b]  (= esI segment base of bucket g)
//   p4: per bucket: block-scan per-(g,b) counts -> staging positions, ONE
//       scattered pass over ep32/epd staging into LDS (+count/deg from q15),
//       LDS scan -> row_ptr+dinv, pass B = staged u32 copied to esI directly,
//       fused fp16 mirror m0 = fp16(feat*dinv).
// Rounds: 4x aggregate, 4 nodes/wave, fp16 gather mirror pre-scaled by
// dinv[src] (ping-pong m0/m1), in-place fp32 chain.
// feat [N,32] f32, src [E] i32, dst [E] i32, mask [E] f32 -> h [N,32] f32.

#define FDIM 32
#define DLO_BITS 8
#define BKT_NODES 256          // nodes per bucket = 1<<DLO_BITS
#define S_FIX 1536             // edges per p3 block (3 x 512)
#define MAXBKT 512             // supports N <= 131072 (src fits 17 bits)
#define MAXNBLK 2048           // p4 pseg capacity (E <= 3.1M)
#define PCAP 5120              // staged edges per bucket (mean 4092 + 16 sigma)

// ---------------- build ----------------

// p3: block-local counting sort of a 1536-edge slice into slim records.
__global__ __launch_bounds__(512) void p3_kernel(const int* __restrict__ src,
                                                 const int* __restrict__ dst,
                                                 const float* __restrict__ mask,
                                                 int* __restrict__ lofsT,
                                                 unsigned* __restrict__ ep32,
                                                 unsigned char* __restrict__ epd,
                                                 int NBLKp, int nbkt, int E) {
    __shared__ int sdst[S_FIX];
    __shared__ unsigned spk[S_FIX];   // src | q15(mask) << 17
    __shared__ int lh[MAXBKT];
    __shared__ int ws[8];
    int b = blockIdx.x;
    int tid = threadIdx.x;
    int e0 = b * S_FIX;
    int n = E - e0;
    if (n > S_FIX) n = S_FIX;
    if (n < 0) n = 0;
    for (int t = tid; t < n; t += 512) {
        sdst[t] = dst[e0 + t];
        float mk = mask[e0 + t];
        int wq = (int)(mk * 32768.0f + 0.5f);
        if (wq > 32767) wq = 32767;
        spk[t] = (unsigned)src[e0 + t] | ((unsigned)wq << 17);
    }
    lh[tid] = 0;  // blockDim == MAXBKT == 512
    __syncthreads();
    for (int t = tid; t < n; t += 512) atomicAdd(&lh[sdst[t] >> DLO_BITS], 1);
    __syncthreads();
    int v = lh[tid];
    int lane = tid & 63, wv = tid >> 6;
    int x = v;
#pragma unroll
    for (int o = 1; o < 64; o <<= 1) {
        int y = __shfl_up(x, o);
        if (lane >= o) x += y;
    }
    if (lane == 63) ws[wv] = x;
    __syncthreads();
    int add = 0;
    for (int i = 0; i < wv; ++i) add += ws[i];
    x += add;
    int excl = x - v;
    lh[tid] = excl;
    if (tid < nbkt) lofsT[(size_t)tid * NBLKp + b] = excl;
    if (tid == 0) lofsT[(size_t)nbkt * NBLKp + b] = n;
    __syncthreads();
    for (int t = tid; t < n; t += 512) {
        int d = sdst[t];
        int g = d >> DLO_BITS;
        int pos = e0 + atomicAdd(&lh[g], 1);
        ep32[pos] = spk[t];
        epd[pos] = (unsigned char)(d & (BKT_NODES - 1));
    }
}

// R[g] = sum_b lofsT[g*NBLKp + b]
__global__ void scanR_kernel(const int* __restrict__ lofsT, int* __restrict__ R, int NBLKp) {
    int g = blockIdx.x;
    int tid = threadIdx.x;  // 256
    int s = 0;
    for (int t = tid; t < NBLKp; t += 256) s += lofsT[(size_t)g * NBLKp + t];
#pragma unroll
    for (int o = 1; o < 64; o <<= 1) s += __shfl_xor(s, o);
    __shared__ int wsum[4];
    int lane = tid & 63, wv = tid >> 6;
    if (lane == 0) wsum[wv] = s;
    __syncthreads();
    if (tid == 0) R[g] = wsum[0] + wsum[1] + wsum[2] + wsum[3];
}

// p4: one 512-thread block per bucket. LDS-staged single scattered pass.
__global__ __launch_bounds__(512) void p4_kernel(const unsigned* __restrict__ ep32,
                                                 const unsigned char* __restrict__ epd,
                                                 const int* __restrict__ lofsT,
                                                 const int* __restrict__ R,
                                                 unsigned* __restrict__ esI,
                                                 int* __restrict__ row_ptr,
                                                 float* __restrict__ dinv,
                                                 const float4* __restrict__ feat,
                                                 uint2* __restrict__ m0,
                                                 int NBLKp, int nbkt, int N, int E) {
    __shared__ unsigned su32[PCAP];        // 20KB
    __shared__ unsigned char sdlo[PCAP];   // 5KB
    __shared__ int pseg[MAXNBLK];          // 8KB: per-(g,b) staging base
    __shared__ int lcnt[BKT_NODES];
    __shared__ int lofs[BKT_NODES];
    __shared__ float ldeg[BKT_NODES];
    __shared__ int ws[8];
    __shared__ int carry;
    int g = blockIdx.x;
    int tid = threadIdx.x;
    int lane = tid & 63, wv = tid >> 6;
    if (tid < BKT_NODES) { lcnt[tid] = 0; ldeg[tid] = 0.0f; }
    if (tid == 0) carry = 0;
    __syncthreads();
    int segbase = R[g];
    // block-exclusive-scan of per-(g,b) counts -> pseg, total T in carry
    for (int base = 0; base < NBLKp; base += 512) {
        int b = base + tid;
        int c = 0;
        if (b < NBLKp)
            c = lofsT[(size_t)(g + 1) * NBLKp + b] - lofsT[(size_t)g * NBLKp + b];
        int x = c;
#pragma unroll
        for (int o = 1; o < 64; o <<= 1) {
            int y = __shfl_up(x, o);
            if (lane >= o) x += y;
        }
        if (lane == 63) ws[wv] = x;
        __syncthreads();
        int add = 0;
        for (int i = 0; i < wv; ++i) add += ws[i];
        x += add;
        int cc = carry;
        if (b < NBLKp) pseg[b] = x - c + cc;
        __syncthreads();
        if (tid == 511) carry = cc + x;
        __syncthreads();
    }
    int T = carry;
    bool staged = (T <= PCAP);
    // pass A: scattered read of ep32/epd (ONCE) -> stage + count + deg.
    int grp = tid >> 2, l4 = tid & 3;
    for (int b = grp; b < NBLKp; b += 128) {
        int st = lofsT[(size_t)g * NBLKp + b];
        int en = lofsT[(size_t)(g + 1) * NBLKp + b];
        int base = b * S_FIX;
        int pb = pseg[b];
        for (int i = st + l4; i < en; i += 4) {
            unsigned v = ep32[base + i];
            int dlo = epd[base + i];
            atomicAdd(&lcnt[dlo], 1);
            atomicAdd(&ldeg[dlo], (float)(v >> 17) * (1.0f / 32768.0f));
            if (staged) { su32[pb + (i - st)] = v; sdlo[pb + (i - st)] = (unsigned char)dlo; }
        }
    }
    __syncthreads();
    // 512-wide exclusive scan of lcnt (zero-padded)
    int v = (tid < BKT_NODES) ? lcnt[tid] : 0;
    int x = v;
#pragma unroll
    for (int o = 1; o < 64; o <<= 1) {
        int y = __shfl_up(x, o);
        if (lane >= o) x += y;
    }
    if (lane == 63) ws[wv] = x;
    __syncthreads();
    int add = 0;
    for (int i = 0; i < wv; ++i) add += ws[i];
    x += add;
    int excl = x - v;
    if (tid < BKT_NODES) {
        lofs[tid] = excl;
        int node = g * BKT_NODES + tid;
        if (node < N) {
            row_ptr[node] = segbase + excl;
            float d = ldeg[tid];
            d = d > 1.0f ? d : 1.0f;
            float di = 1.0f / sqrtf(d);  // precise: reused across 4 rounds
            dinv[node] = di;
            ldeg[tid] = di;  // ldeg now holds dinv
        }
    }
    if (g == 0 && tid == 0) row_ptr[N] = E;
    __syncthreads();
    if (tid < BKT_NODES) lcnt[tid] = 0;  // reuse as rank counters
    __syncthreads();
    // pass B: rank + esI copy (staged u32 IS the final record)
    if (staged) {
        for (int k = tid; k < T; k += 512) {
            unsigned v2 = su32[k];
            int dlo = sdlo[k];
            int r = atomicAdd(&lcnt[dlo], 1);
            esI[segbase + lofs[dlo] + r] = v2;
        }
    } else {
        for (int b = grp; b < NBLKp; b += 128) {
            int st = lofsT[(size_t)g * NBLKp + b];
            int en = lofsT[(size_t)(g + 1) * NBLKp + b];
            int base = b * S_FIX;
            for (int i = st + l4; i < en; i += 4) {
                unsigned v2 = ep32[base + i];
                int dlo = epd[base + i];
                int r = atomicAdd(&lcnt[dlo], 1);
                esI[segbase + lofs[dlo] + r] = v2;
            }
        }
    }
    // fused mirror init (ldeg holds dinv)
    int base_node = g * BKT_NODES;
    for (int t = tid; t < BKT_NODES * 8; t += 512) {
        int nl = t >> 3;
        int n2 = base_node + nl;
        if (n2 >= N) break;
        float di = ldeg[nl];
        float4 f = feat[(size_t)n2 * 8 + (t & 7)];
        __half2 a = __float22half2_rn(make_float2(f.x * di, f.y * di));
        __half2 bb = __float22half2_rn(make_float2(f.z * di, f.w * di));
        uint2 m;
        m.x = *(unsigned*)&a;
        m.y = *(unsigned*)&bb;
        m0[(size_t)n2 * 8 + (t & 7)] = m;
    }
}

// ---------------- aggregate (unchanged) ----------------
template <int MODE>
__global__ __launch_bounds__(256) void aggregate_kernel(
    const float4* __restrict__ fown, float4* __restrict__ fwr,
    const uint2* __restrict__ gin, uint2* __restrict__ gout,
    float4* __restrict__ out,
    const int* __restrict__ row_ptr, const unsigned* __restrict__ es,
    const float* __restrict__ dinv, float theta, float theta0, int N) {
    int wave = (blockIdx.x * blockDim.x + threadIdx.x) >> 6;
    int lane = threadIdx.x & 63;
    int node = wave * 4 + (lane >> 4);
    if (node >= N) return;
    int l16 = lane & 15;
    int c = l16 & 7;
    int q = l16 >> 3;  // 0..1
    int b = row_ptr[node];
    int e = row_ptr[node + 1];
    float ax = 0.f, ay = 0.f, az = 0.f, aw = 0.f;
    float bx = 0.f, by = 0.f, bz = 0.f, bw = 0.f;
    int i = b + q;
    for (; i + 2 < e; i += 4) {
        unsigned e0 = es[i];
        unsigned e1 = es[i + 2];
        float w0 = (float)(e0 >> 17) * (1.0f / 32768.0f);
        float w1 = (float)(e1 >> 17) * (1.0f / 32768.0f);
        uint2 r0 = gin[(size_t)(e0 & 0x1FFFF) * 8 + c];
        uint2 r1 = gin[(size_t)(e1 & 0x1FFFF) * 8 + c];
        float2 p0 = __half22float2(*(const __half2*)&r0.x);
        float2 p1 = __half22float2(*(const __half2*)&r0.y);
        float2 p2 = __half22float2(*(const __half2*)&r1.x);
        float2 p3 = __half22float2(*(const __half2*)&r1.y);
        ax += w0 * p0.x; ay += w0 * p0.y; az += w0 * p1.x; aw += w0 * p1.y;
        bx += w1 * p2.x; by += w1 * p2.y; bz += w1 * p3.x; bw += w1 * p3.y;
    }
    if (i < e) {
        unsigned e0 = es[i];
        float w0 = (float)(e0 >> 17) * (1.0f / 32768.0f);
        uint2 r0 = gin[(size_t)(e0 & 0x1FFFF) * 8 + c];
        float2 p0 = __half22float2(*(const __half2*)&r0.x);
        float2 p1 = __half22float2(*(const __half2*)&r0.y);
        ax += w0 * p0.x; ay += w0 * p0.y; az += w0 * p1.x; aw += w0 * p1.y;
    }
    ax += bx; ay += by; az += bz; aw += bw;
    ax += __shfl_xor(ax, 8);
    ay += __shfl_xor(ay, 8);
    az += __shfl_xor(az, 8);
    aw += __shfl_xor(aw, 8);
    float4 fav = fown[(size_t)node * 8 + c];
    float di = dinv[node];
    float fx = fav.x - ax * di;
    float fy = fav.y - ay * di;
    float fz = fav.z - az * di;
    float fw = fav.w - aw * di;
    if (MODE != 2) {
        if (q == 0) {
            float4 t; t.x = fx; t.y = fy; t.z = fz; t.w = fw;
            fwr[(size_t)node * 8 + c] = t;
            __half2 a = __float22half2_rn(make_float2(fx * di, fy * di));
            __half2 bb = __float22half2_rn(make_float2(fz * di, fw * di));
            uint2 m;
            m.x = *(unsigned*)&a;
            m.y = *(unsigned*)&bb;
            gout[(size_t)node * 8 + c] = m;
        } else {
            float4 o;
            if (MODE == 1) {
                o.x = theta0 * fav.x + theta * fx;
                o.y = theta0 * fav.y + theta * fy;
                o.z = theta0 * fav.z + theta * fz;
                o.w = theta0 * fav.w + theta * fw;
            } else {
                o = out[(size_t)node * 8 + c];
                o.x += theta * fx; o.y += theta * fy;
                o.z += theta * fz; o.w += theta * fw;
            }
            out[(size_t)node * 8 + c] = o;
        }
    } else {
        if (q == 1) {
            float4 o = out[(size_t)node * 8 + c];
            o.x += theta * fx; o.y += theta * fy;
            o.z += theta * fz; o.w += theta * fw;
            out[(size_t)node * 8 + c] = o;
        }
    }
}

// ---------------- fallback: atomic scatter path ----------------

__global__ void fb_deg_kernel(const int* __restrict__ dst, const float* __restrict__ mask,
                              float* __restrict__ deg, int E) {
    int e = blockIdx.x * blockDim.x + threadIdx.x;
    if (e < E) atomicAdd(&deg[dst[e]], mask[e]);
}

__global__ void fb_dinv_kernel(float* __restrict__ deg, int N) {
    int i = blockIdx.x * blockDim.x + threadIdx.x;
    if (i < N) {
        float d = deg[i];
        d = d > 1.0f ? d : 1.0f;
        deg[i] = 1.0f / sqrtf(d);
    }
}

__global__ void fb_init_kernel(const float4* __restrict__ feat, float4* __restrict__ fbuf,
                               float4* __restrict__ out, int n4) {
    int i = blockIdx.x * blockDim.x + threadIdx.x;
    if (i < n4) {
        float4 f = feat[i];
        fbuf[i] = f;
        float4 o;
        o.x = 0.2f * f.x; o.y = 0.2f * f.y; o.z = 0.2f * f.z; o.w = 0.2f * f.w;
        out[i] = o;
    }
}

__global__ void fb_scatter_kernel(const float4* __restrict__ fbuf, const float* __restrict__ dinv,
                                  const int* __restrict__ src, const int* __restrict__ dst,
                                  const float* __restrict__ mask, float* __restrict__ agg, int E) {
    int t = blockIdx.x * blockDim.x + threadIdx.x;
    int e = t >> 3;
    if (e >= E) return;
    int c4 = t & 7;
    int s = src[e];
    int d = dst[e];
    float w = mask[e] * dinv[s];
    float4 f = fbuf[s * 8 + c4];
    float* ap = agg + (size_t)d * FDIM + c4 * 4;
    atomicAdd(ap + 0, f.x * w);
    atomicAdd(ap + 1, f.y * w);
    atomicAdd(ap + 2, f.z * w);
    atomicAdd(ap + 3, f.w * w);
}

__global__ void fb_update_kernel(float4* __restrict__ fbuf, float4* __restrict__ agg,
                                 const float* __restrict__ dinv, float4* __restrict__ out,
                                 float theta, int n4) {
    int t = blockIdx.x * blockDim.x + threadIdx.x;
    if (t >= n4) return;
    int node = t >> 3;
    float di = dinv[node];
    float4 a = agg[t];
    float4 z; z.x = 0.f; z.y = 0.f; z.z = 0.f; z.w = 0.f;
    agg[t] = z;
    float4 f = fbuf[t];
    f.x -= a.x * di; f.y -= a.y * di; f.z -= a.z * di; f.w -= a.w * di;
    fbuf[t] = f;
    float4 o = out[t];
    o.x += theta * f.x; o.y += theta * f.y; o.z += theta * f.z; o.w += theta * f.w;
    out[t] = o;
}

// ---------------- launch ----------------

static inline size_t align_up(size_t x) { return (x + 63) & ~(size_t)63; }  // 64-elem align

extern "C" void kernel_launch(void* const* d_in, const int* in_sizes, int n_in,
                              void* d_out, int out_size, void* d_ws, size_t ws_size,
                              hipStream_t stream) {
    const float* feat = (const float*)d_in[0];
    const int* src = (const int*)d_in[1];
    const int* dst = (const int*)d_in[2];
    const float* mask = (const float*)d_in[3];
    float* out = (float*)d_out;

    const int N = in_sizes[0] / FDIM;
    const int E = in_sizes[1];
    const float thetas[5] = {0.2f, -0.4f, 0.3f, -0.15f, 0.05f};
    const int B = 256;

    const int nbkt = (N + BKT_NODES - 1) / BKT_NODES;
    const int NBLKp = (E + S_FIX - 1) / S_FIX;

    // ws layout (4B elements, 64-elem aligned) — ALL PERSISTENT.
    size_t o_dinv = 0;                                            // N
    size_t o_rp    = align_up(o_dinv + N);                        // N+1
    size_t o_esI   = align_up(o_rp + N + 1);                      // E
    size_t o_m0    = align_up(o_esI + (size_t)E);                 // 16N
    size_t o_m1    = align_up(o_m0 + (size_t)N * 16);             // 16N
    size_t o_ep32  = align_up(o_m1 + (size_t)N * 16);             // E
    size_t o_epd   = align_up(o_ep32 + (size_t)E);                // E bytes -> E/4
    size_t o_lofsT = align_up(o_epd + ((size_t)E + 3) / 4);       // (nbkt+1)*NBLKp
    size_t o_R     = align_up(o_lofsT + (size_t)(nbkt + 1) * NBLKp);  // nbkt+1
    size_t o_f     = align_up(o_R + nbkt + 1);                    // 32N
    size_t need = (o_f + (size_t)N * FDIM) * 4;

    float* wsf = (float*)d_ws;
    int* wsi = (int*)d_ws;

    int nbE = (E + B - 1) / B;
    int nbN = (N + B - 1) / B;

    if (ws_size >= need && N <= (1 << 17) && nbkt <= MAXBKT && NBLKp <= MAXNBLK) {
        float* dinv = wsf + o_dinv;
        int* row_ptr = wsi + o_rp;
        unsigned* esI = (unsigned*)(wsi + o_esI);
        uint2* m0 = (uint2*)(wsi + o_m0);
        uint2* m1 = (uint2*)(wsi + o_m1);
        unsigned* ep32 = (unsigned*)(wsi + o_ep32);
        unsigned char* epd = (unsigned char*)(wsi + o_epd);
        int* lofsT = wsi + o_lofsT;
        int* R = wsi + o_R;
        float4* f = (float4*)(wsf + o_f);

        p3_kernel<<<NBLKp, 512, 0, stream>>>(src, dst, mask, lofsT, ep32, epd,
                                             NBLKp, nbkt, E);
        scanR_kernel<<<nbkt + 1, 256, 0, stream>>>(lofsT, R, NBLKp);
        p4_kernel<<<nbkt, 512, 0, stream>>>(ep32, epd, lofsT, R, esI, row_ptr, dinv,
                                            (const float4*)feat, m0, NBLKp, nbkt, N, E);

        int aggWaves = (N + 3) / 4;
        int agg_blocks = (aggWaves * 64 + B - 1) / B;
        aggregate_kernel<1><<<agg_blocks, B, 0, stream>>>((const float4*)feat, f, m0, m1,
                                                          (float4*)out, row_ptr, esI, dinv,
                                                          thetas[1], thetas[0], N);
        aggregate_kernel<0><<<agg_blocks, B, 0, stream>>>(f, f, m1, m0, (float4*)out,
                                                          row_ptr, esI, dinv, thetas[2], 0.f, N);
        aggregate_kernel<0><<<agg_blocks, B, 0, stream>>>(f, f, m0, m1, (float4*)out,
                                                          row_ptr, esI, dinv, thetas[3], 0.f, N);
        aggregate_kernel<2><<<agg_blocks, B, 0, stream>>>(f, f, m1, m0, (float4*)out,
                                                          row_ptr, esI, dinv, thetas[4], 0.f, N);
    } else {
        // fallback: atomic-scatter path
        float* deg = wsf;                       // N
        float* agg = deg + align_up(N);         // 32N
        float* fbuf = agg + (size_t)N * FDIM;   // 32N

        hipMemsetAsync(d_ws, 0, (align_up(N) + (size_t)N * FDIM) * 4, stream);
        fb_deg_kernel<<<nbE, B, 0, stream>>>(dst, mask, deg, E);
        fb_dinv_kernel<<<nbN, B, 0, stream>>>(deg, N);

        int n4 = N * (FDIM / 4);
        fb_init_kernel<<<(n4 + B - 1) / B, B, 0, stream>>>((const float4*)feat, (float4*)fbuf,
                                                           (float4*)out, n4);
        long long sc_threads = (long long)E * 8;
        int sc_blocks = (int)((sc_threads + B - 1) / B);
        for (int k = 1; k < 5; ++k) {
            fb_scatter_kernel<<<sc_blocks, B, 0, stream>>>((const float4*)fbuf, deg, src, dst,
                                                           mask, agg, E);
            fb_update_kernel<<<(n4 + B - 1) / B, B, 0, stream>>>((float4*)fbuf, (float4*)agg,
                                                                 deg, (float4*)out, thetas[k], n4);
        }
    }
}

// Round 15
// 170.851 us; speedup vs baseline: 1.0401x; 1.0401x over previous
//
#include <hip/hip_runtime.h>
#include <hip/hip_fp16.h>

// PolyConv via CSR-gather. Build = block-local LDS counting sort (R13 form):
//   p3: block sorts its 1536-edge slice by bucket (g=dst>>8) into its own
//       contiguous esp window (streaming), emits lofsT[g][b].
//   scanR: R[g] = sum_b lofsT[g][b]  (= esI segment base of bucket g)
//   p4: per bucket: block-scan per-(g,b) counts -> staging positions, ONE
//       scattered pass over esp staging the bucket into LDS (+count/deg),
//       LDS scan -> row_ptr+dinv, linear LDS pass -> packed esI, fused fp16
//       mirror m0 = fp16(feat*dinv).
// Rounds: 4x aggregate, 4 nodes/wave, 4-deep unrolled gather (8 in flight
// per node), fp16 mirror pre-scaled by dinv[src] (ping-pong m0/m1),
// in-place fp32 chain.
// feat [N,32] f32, src [E] i32, dst [E] i32, mask [E] f32 -> h [N,32] f32.

#define FDIM 32
#define DLO_BITS 8
#define BKT_NODES 256          // nodes per bucket = 1<<DLO_BITS
#define S_FIX 1536             // edges per p3 block (3 x 512)
#define MAXBKT 512             // supports N <= 131072 (src fits 17 bits)
#define MAXNBLK 2048           // p4 pseg capacity (E <= 3.1M)
#define PCAP 5120              // staged edges per bucket (mean 4092 + 16 sigma)

// ---------------- build (R13, proven) ----------------

__global__ __launch_bounds__(512) void p3_kernel(const int* __restrict__ src,
                                                 const int* __restrict__ dst,
                                                 const float* __restrict__ mask,
                                                 int* __restrict__ lofsT,
                                                 int2* __restrict__ esp,
                                                 int NBLKp, int nbkt, int E) {
    __shared__ int sdst[S_FIX];
    __shared__ int ssrc[S_FIX];
    __shared__ float smask[S_FIX];
    __shared__ int lh[MAXBKT];
    __shared__ int ws[8];
    int b = blockIdx.x;
    int tid = threadIdx.x;
    int e0 = b * S_FIX;
    int n = E - e0;
    if (n > S_FIX) n = S_FIX;
    if (n < 0) n = 0;
    for (int t = tid; t < n; t += 512) {
        sdst[t] = dst[e0 + t];
        ssrc[t] = src[e0 + t];
        smask[t] = mask[e0 + t];
    }
    lh[tid] = 0;  // blockDim == MAXBKT == 512
    __syncthreads();
    for (int t = tid; t < n; t += 512) atomicAdd(&lh[sdst[t] >> DLO_BITS], 1);
    __syncthreads();
    int v = lh[tid];
    int lane = tid & 63, wv = tid >> 6;
    int x = v;
#pragma unroll
    for (int o = 1; o < 64; o <<= 1) {
        int y = __shfl_up(x, o);
        if (lane >= o) x += y;
    }
    if (lane == 63) ws[wv] = x;
    __syncthreads();
    int add = 0;
    for (int i = 0; i < wv; ++i) add += ws[i];
    x += add;
    int excl = x - v;
    lh[tid] = excl;
    if (tid < nbkt) lofsT[(size_t)tid * NBLKp + b] = excl;
    if (tid == 0) lofsT[(size_t)nbkt * NBLKp + b] = n;
    __syncthreads();
    for (int t = tid; t < n; t += 512) {
        int d = sdst[t];
        int g = d >> DLO_BITS;
        int pos = e0 + atomicAdd(&lh[g], 1);
        int2 vv;
        vv.x = ssrc[t] | ((d & (BKT_NODES - 1)) << 17);
        vv.y = __float_as_int(smask[t]);
        esp[pos] = vv;
    }
}

__global__ void scanR_kernel(const int* __restrict__ lofsT, int* __restrict__ R, int NBLKp) {
    int g = blockIdx.x;
    int tid = threadIdx.x;  // 256
    int s = 0;
    for (int t = tid; t < NBLKp; t += 256) s += lofsT[(size_t)g * NBLKp + t];
#pragma unroll
    for (int o = 1; o < 64; o <<= 1) s += __shfl_xor(s, o);
    __shared__ int wsum[4];
    int lane = tid & 63, wv = tid >> 6;
    if (lane == 0) wsum[wv] = s;
    __syncthreads();
    if (tid == 0) R[g] = wsum[0] + wsum[1] + wsum[2] + wsum[3];
}

__global__ __launch_bounds__(512) void p4_kernel(const int2* __restrict__ esp,
                                                 const int* __restrict__ lofsT,
                                                 const int* __restrict__ R,
                                                 int* __restrict__ esI,
                                                 int* __restrict__ row_ptr,
                                                 float* __restrict__ dinv,
                                                 const float4* __restrict__ feat,
                                                 uint2* __restrict__ m0,
                                                 int NBLKp, int nbkt, int N, int E) {
    __shared__ int2 sstage[PCAP];      // 40KB
    __shared__ int pseg[MAXNBLK];      // 8KB
    __shared__ int lcnt[BKT_NODES];
    __shared__ int lofs[BKT_NODES];
    __shared__ float ldeg[BKT_NODES];
    __shared__ int ws[8];
    __shared__ int carry;
    int g = blockIdx.x;
    int tid = threadIdx.x;
    int lane = tid & 63, wv = tid >> 6;
    if (tid < BKT_NODES) { lcnt[tid] = 0; ldeg[tid] = 0.0f; }
    if (tid == 0) carry = 0;
    __syncthreads();
    int segbase = R[g];
    for (int base = 0; base < NBLKp; base += 512) {
        int b = base + tid;
        int c = 0;
        if (b < NBLKp)
            c = lofsT[(size_t)(g + 1) * NBLKp + b] - lofsT[(size_t)g * NBLKp + b];
        int x = c;
#pragma unroll
        for (int o = 1; o < 64; o <<= 1) {
            int y = __shfl_up(x, o);
            if (lane >= o) x += y;
        }
        if (lane == 63) ws[wv] = x;
        __syncthreads();
        int add = 0;
        for (int i = 0; i < wv; ++i) add += ws[i];
        x += add;
        int cc = carry;
        if (b < NBLKp) pseg[b] = x - c + cc;
        __syncthreads();
        if (tid == 511) carry = cc + x;
        __syncthreads();
    }
    int T = carry;
    bool staged = (T <= PCAP);
    int grp = tid >> 2, l4 = tid & 3;
    for (int b = grp; b < NBLKp; b += 128) {
        int st = lofsT[(size_t)g * NBLKp + b];
        int en = lofsT[(size_t)(g + 1) * NBLKp + b];
        int base = b * S_FIX;
        int pb = pseg[b];
        for (int i = st + l4; i < en; i += 4) {
            int2 v = esp[base + i];
            int dlo = v.x >> 17;
            atomicAdd(&lcnt[dlo], 1);
            atomicAdd(&ldeg[dlo], __int_as_float(v.y));
            if (staged) sstage[pb + (i - st)] = v;
        }
    }
    __syncthreads();
    int v = (tid < BKT_NODES) ? lcnt[tid] : 0;
    int x = v;
#pragma unroll
    for (int o = 1; o < 64; o <<= 1) {
        int y = __shfl_up(x, o);
        if (lane >= o) x += y;
    }
    if (lane == 63) ws[wv] = x;
    __syncthreads();
    int add = 0;
    for (int i = 0; i < wv; ++i) add += ws[i];
    x += add;
    int excl = x - v;
    if (tid < BKT_NODES) {
        lofs[tid] = excl;
        int node = g * BKT_NODES + tid;
        if (node < N) {
            row_ptr[node] = segbase + excl;
            float d = ldeg[tid];
            d = d > 1.0f ? d : 1.0f;
            float di = 1.0f / sqrtf(d);  // precise: reused across 4 rounds
            dinv[node] = di;
            ldeg[tid] = di;  // ldeg now holds dinv
        }
    }
    if (g == 0 && tid == 0) row_ptr[N] = E;
    __syncthreads();
    if (tid < BKT_NODES) lcnt[tid] = 0;
    __syncthreads();
    if (staged) {
        for (int k = tid; k < T; k += 512) {
            int2 v2 = sstage[k];
            int dlo = v2.x >> 17;
            int r = atomicAdd(&lcnt[dlo], 1);
            float mk = __int_as_float(v2.y);
            int wq = (int)(mk * 32768.0f + 0.5f);
            if (wq > 32767) wq = 32767;
            esI[segbase + lofs[dlo] + r] = (v2.x & 0x1FFFF) | (wq << 17);
        }
    } else {
        for (int b = grp; b < NBLKp; b += 128) {
            int st = lofsT[(size_t)g * NBLKp + b];
            int en = lofsT[(size_t)(g + 1) * NBLKp + b];
            int base = b * S_FIX;
            for (int i = st + l4; i < en; i += 4) {
                int2 v2 = esp[base + i];
                int dlo = v2.x >> 17;
                int r = atomicAdd(&lcnt[dlo], 1);
                float mk = __int_as_float(v2.y);
                int wq = (int)(mk * 32768.0f + 0.5f);
                if (wq > 32767) wq = 32767;
                esI[segbase + lofs[dlo] + r] = (v2.x & 0x1FFFF) | (wq << 17);
            }
        }
    }
    int base_node = g * BKT_NODES;
    for (int t = tid; t < BKT_NODES * 8; t += 512) {
        int nl = t >> 3;
        int n2 = base_node + nl;
        if (n2 >= N) break;
        float di = ldeg[nl];
        float4 f = feat[(size_t)n2 * 8 + (t & 7)];
        __half2 a = __float22half2_rn(make_float2(f.x * di, f.y * di));
        __half2 bb = __float22half2_rn(make_float2(f.z * di, f.w * di));
        uint2 m;
        m.x = *(unsigned*)&a;
        m.y = *(unsigned*)&bb;
        m0[(size_t)n2 * 8 + (t & 7)] = m;
    }
}

// ---------------- aggregate: 4 nodes/wave, 4-deep unroll ----------------
// 16 lanes/node: c = lane&7 (uint2 chunk of the 64B fp16 row), q = (lane>>3)&1
// (2-way edge parallel). 4-deep unroll = 8 gathers in flight per node,
// 32 per wave. Gather pre-scaled by dinv[src]; edge = {src:17|q15(mask):15}.
template <int MODE>
__global__ __launch_bounds__(256) void aggregate_kernel(
    const float4* __restrict__ fown, float4* __restrict__ fwr,
    const uint2* __restrict__ gin, uint2* __restrict__ gout,
    float4* __restrict__ out,
    const int* __restrict__ row_ptr, const int* __restrict__ es,
    const float* __restrict__ dinv, float theta, float theta0, int N) {
    int wave = (blockIdx.x * blockDim.x + threadIdx.x) >> 6;
    int lane = threadIdx.x & 63;
    int node = wave * 4 + (lane >> 4);
    if (node >= N) return;
    int l16 = lane & 15;
    int c = l16 & 7;
    int q = l16 >> 3;  // 0..1
    int b = row_ptr[node];
    int e = row_ptr[node + 1];
    float ax = 0.f, ay = 0.f, az = 0.f, aw = 0.f;
    float bx = 0.f, by = 0.f, bz = 0.f, bw = 0.f;
    int i = b + q;
    for (; i + 6 < e; i += 8) {
        int e0 = es[i];
        int e1 = es[i + 2];
        int e2 = es[i + 4];
        int e3 = es[i + 6];
        float w0 = (float)((unsigned)e0 >> 17) * (1.0f / 32768.0f);
        float w1 = (float)((unsigned)e1 >> 17) * (1.0f / 32768.0f);
        float w2 = (float)((unsigned)e2 >> 17) * (1.0f / 32768.0f);
        float w3 = (float)((unsigned)e3 >> 17) * (1.0f / 32768.0f);
        uint2 r0 = gin[(size_t)(e0 & 0x1FFFF) * 8 + c];
        uint2 r1 = gin[(size_t)(e1 & 0x1FFFF) * 8 + c];
        uint2 r2 = gin[(size_t)(e2 & 0x1FFFF) * 8 + c];
        uint2 r3 = gin[(size_t)(e3 & 0x1FFFF) * 8 + c];
        float2 p0 = __half22float2(*(const __half2*)&r0.x);
        float2 p1 = __half22float2(*(const __half2*)&r0.y);
        float2 p2 = __half22float2(*(const __half2*)&r1.x);
        float2 p3 = __half22float2(*(const __half2*)&r1.y);
        float2 p4 = __half22float2(*(const __half2*)&r2.x);
        float2 p5 = __half22float2(*(const __half2*)&r2.y);
        float2 p6 = __half22float2(*(const __half2*)&r3.x);
        float2 p7 = __half22float2(*(const __half2*)&r3.y);
        ax += w0 * p0.x; ay += w0 * p0.y; az += w0 * p1.x; aw += w0 * p1.y;
        bx += w1 * p2.x; by += w1 * p2.y; bz += w1 * p3.x; bw += w1 * p3.y;
        ax += w2 * p4.x; ay += w2 * p4.y; az += w2 * p5.x; aw += w2 * p5.y;
        bx += w3 * p6.x; by += w3 * p6.y; bz += w3 * p7.x; bw += w3 * p7.y;
    }
    for (; i < e; i += 2) {
        int e0 = es[i];
        float w0 = (float)((unsigned)e0 >> 17) * (1.0f / 32768.0f);
        uint2 r0 = gin[(size_t)(e0 & 0x1FFFF) * 8 + c];
        float2 p0 = __half22float2(*(const __half2*)&r0.x);
        float2 p1 = __half22float2(*(const __half2*)&r0.y);
        ax += w0 * p0.x; ay += w0 * p0.y; az += w0 * p1.x; aw += w0 * p1.y;
    }
    ax += bx; ay += by; az += bz; aw += bw;
    ax += __shfl_xor(ax, 8);
    ay += __shfl_xor(ay, 8);
    az += __shfl_xor(az, 8);
    aw += __shfl_xor(aw, 8);
    float4 fav = fown[(size_t)node * 8 + c];
    float di = dinv[node];
    float fx = fav.x - ax * di;
    float fy = fav.y - ay * di;
    float fz = fav.z - az * di;
    float fw = fav.w - aw * di;
    if (MODE != 2) {
        if (q == 0) {
            float4 t; t.x = fx; t.y = fy; t.z = fz; t.w = fw;
            fwr[(size_t)node * 8 + c] = t;
            __half2 a = __float22half2_rn(make_float2(fx * di, fy * di));
            __half2 bb = __float22half2_rn(make_float2(fz * di, fw * di));
            uint2 m;
            m.x = *(unsigned*)&a;
            m.y = *(unsigned*)&bb;
            gout[(size_t)node * 8 + c] = m;
        } else {
            float4 o;
            if (MODE == 1) {
                o.x = theta0 * fav.x + theta * fx;
                o.y = theta0 * fav.y + theta * fy;
                o.z = theta0 * fav.z + theta * fz;
                o.w = theta0 * fav.w + theta * fw;
            } else {
                o = out[(size_t)node * 8 + c];
                o.x += theta * fx; o.y += theta * fy;
                o.z += theta * fz; o.w += theta * fw;
            }
            out[(size_t)node * 8 + c] = o;
        }
    } else {
        if (q == 1) {
            float4 o = out[(size_t)node * 8 + c];
            o.x += theta * fx; o.y += theta * fy;
            o.z += theta * fz; o.w += theta * fw;
            out[(size_t)node * 8 + c] = o;
        }
    }
}

// ---------------- fallback: atomic scatter path ----------------

__global__ void fb_deg_kernel(const int* __restrict__ dst, const float* __restrict__ mask,
                              float* __restrict__ deg, int E) {
    int e = blockIdx.x * blockDim.x + threadIdx.x;
    if (e < E) atomicAdd(&deg[dst[e]], mask[e]);
}

__global__ void fb_dinv_kernel(float* __restrict__ deg, int N) {
    int i = blockIdx.x * blockDim.x + threadIdx.x;
    if (i < N) {
        float d = deg[i];
        d = d > 1.0f ? d : 1.0f;
        deg[i] = 1.0f / sqrtf(d);
    }
}

__global__ void fb_init_kernel(const float4* __restrict__ feat, float4* __restrict__ fbuf,
                               float4* __restrict__ out, int n4) {
    int i = blockIdx.x * blockDim.x + threadIdx.x;
    if (i < n4) {
        float4 f = feat[i];
        fbuf[i] = f;
        float4 o;
        o.x = 0.2f * f.x; o.y = 0.2f * f.y; o.z = 0.2f * f.z; o.w = 0.2f * f.w;
        out[i] = o;
    }
}

__global__ void fb_scatter_kernel(const float4* __restrict__ fbuf, const float* __restrict__ dinv,
                                  const int* __restrict__ src, const int* __restrict__ dst,
                                  const float* __restrict__ mask, float* __restrict__ agg, int E) {
    int t = blockIdx.x * blockDim.x + threadIdx.x;
    int e = t >> 3;
    if (e >= E) return;
    int c4 = t & 7;
    int s = src[e];
    int d = dst[e];
    float w = mask[e] * dinv[s];
    float4 f = fbuf[s * 8 + c4];
    float* ap = agg + (size_t)d * FDIM + c4 * 4;
    atomicAdd(ap + 0, f.x * w);
    atomicAdd(ap + 1, f.y * w);
    atomicAdd(ap + 2, f.z * w);
    atomicAdd(ap + 3, f.w * w);
}

__global__ void fb_update_kernel(float4* __restrict__ fbuf, float4* __restrict__ agg,
                                 const float* __restrict__ dinv, float4* __restrict__ out,
                                 float theta, int n4) {
    int t = blockIdx.x * blockDim.x + threadIdx.x;
    if (t >= n4) return;
    int node = t >> 3;
    float di = dinv[node];
    float4 a = agg[t];
    float4 z; z.x = 0.f; z.y = 0.f; z.z = 0.f; z.w = 0.f;
    agg[t] = z;
    float4 f = fbuf[t];
    f.x -= a.x * di; f.y -= a.y * di; f.z -= a.z * di; f.w -= a.w * di;
    fbuf[t] = f;
    float4 o = out[t];
    o.x += theta * f.x; o.y += theta * f.y; o.z += theta * f.z; o.w += theta * f.w;
    out[t] = o;
}

// ---------------- launch ----------------

static inline size_t align_up(size_t x) { return (x + 63) & ~(size_t)63; }  // 64-elem align

extern "C" void kernel_launch(void* const* d_in, const int* in_sizes, int n_in,
                              void* d_out, int out_size, void* d_ws, size_t ws_size,
                              hipStream_t stream) {
    const float* feat = (const float*)d_in[0];
    const int* src = (const int*)d_in[1];
    const int* dst = (const int*)d_in[2];
    const float* mask = (const float*)d_in[3];
    float* out = (float*)d_out;

    const int N = in_sizes[0] / FDIM;
    const int E = in_sizes[1];
    const float thetas[5] = {0.2f, -0.4f, 0.3f, -0.15f, 0.05f};
    const int B = 256;

    const int nbkt = (N + BKT_NODES - 1) / BKT_NODES;
    const int NBLKp = (E + S_FIX - 1) / S_FIX;

    // ws layout (4B elements, 64-elem aligned) — ALL PERSISTENT.
    size_t o_dinv = 0;                                            // N
    size_t o_rp    = align_up(o_dinv + N);                        // N+1
    size_t o_esI   = align_up(o_rp + N + 1);                      // E
    size_t o_m0    = align_up(o_esI + (size_t)E);                 // 16N
    size_t o_m1    = align_up(o_m0 + (size_t)N * 16);             // 16N
    size_t o_esp   = align_up(o_m1 + (size_t)N * 16);             // 2E
    size_t o_lofsT = align_up(o_esp + 2 * (size_t)E);             // (nbkt+1)*NBLKp
    size_t o_R     = align_up(o_lofsT + (size_t)(nbkt + 1) * NBLKp);  // nbkt+1
    size_t o_f     = align_up(o_R + nbkt + 1);                    // 32N
    size_t need = (o_f + (size_t)N * FDIM) * 4;

    float* wsf = (float*)d_ws;
    int* wsi = (int*)d_ws;

    int nbE = (E + B - 1) / B;
    int nbN = (N + B - 1) / B;

    if (ws_size >= need && N <= (1 << 17) && nbkt <= MAXBKT && NBLKp <= MAXNBLK) {
        float* dinv = wsf + o_dinv;
        int* row_ptr = wsi + o_rp;
        int* esI = wsi + o_esI;
        uint2* m0 = (uint2*)(wsi + o_m0);
        uint2* m1 = (uint2*)(wsi + o_m1);
        int2* esp = (int2*)(wsi + o_esp);
        int* lofsT = wsi + o_lofsT;
        int* R = wsi + o_R;
        float4* f = (float4*)(wsf + o_f);

        p3_kernel<<<NBLKp, 512, 0, stream>>>(src, dst, mask, lofsT, esp, NBLKp, nbkt, E);
        scanR_kernel<<<nbkt + 1, 256, 0, stream>>>(lofsT, R, NBLKp);
        p4_kernel<<<nbkt, 512, 0, stream>>>(esp, lofsT, R, esI, row_ptr, dinv,
                                            (const float4*)feat, m0, NBLKp, nbkt, N, E);

        int aggWaves = (N + 3) / 4;
        int agg_blocks = (aggWaves * 64 + B - 1) / B;
        aggregate_kernel<1><<<agg_blocks, B, 0, stream>>>((const float4*)feat, f, m0, m1,
                                                          (float4*)out, row_ptr, esI, dinv,
                                                          thetas[1], thetas[0], N);
        aggregate_kernel<0><<<agg_blocks, B, 0, stream>>>(f, f, m1, m0, (float4*)out,
                                                          row_ptr, esI, dinv, thetas[2], 0.f, N);
        aggregate_kernel<0><<<agg_blocks, B, 0, stream>>>(f, f, m0, m1, (float4*)out,
                                                          row_ptr, esI, dinv, thetas[3], 0.f, N);
        aggregate_kernel<2><<<agg_blocks, B, 0, stream>>>(f, f, m1, m0, (float4*)out,
                                                          row_ptr, esI, dinv, thetas[4], 0.f, N);
    } else {
        // fallback: atomic-scatter path
        float* deg = wsf;                       // N
        float* agg = deg + align_up(N);         // 32N
        float* fbuf = agg + (size_t)N * FDIM;   // 32N

        hipMemsetAsync(d_ws, 0, (align_up(N) + (size_t)N * FDIM) * 4, stream);
        fb_deg_kernel<<<nbE, B, 0, stream>>>(dst, mask, deg, E);
        fb_dinv_kernel<<<nbN, B, 0, stream>>>(deg, N);

        int n4 = N * (FDIM / 4);
        fb_init_kernel<<<(n4 + B - 1) / B, B, 0, stream>>>((const float4*)feat, (float4*)fbuf,
                                                           (float4*)out, n4);
        long long sc_threads = (long long)E * 8;
        int sc_blocks = (int)((sc_threads + B - 1) / B);
        for (int k = 1; k < 5; ++k) {
            fb_scatter_kernel<<<sc_blocks, B, 0, stream>>>((const float4*)fbuf, deg, src, dst,
                                                           mask, agg, E);
            fb_update_kernel<<<(n4 + B - 1) / B, B, 0, stream>>>((float4*)fbuf, (float4*)agg,
                                                                 deg, (float4*)out, thetas[k], n4);
        }
    }
}